// Round 1
// baseline (2097.645 us; speedup 1.0000x reference)
//
#include <hip/hip_runtime.h>

#define NH 16
#define HD 64
#define SEQ 2048
#define HID 1024
#define BQ 64
#define BK 64
#define NER 127   // BQ + BK - 1 rows of dist_emb per tile pair

// ---------------- Projection GEMM: out = X @ W^T + bias ----------------
// X: [M=4096, 1024] row-major; W: [1024,1024] row-major (out-feature rows).
// 64x64 tile per block, 256 threads, 4x4 per thread, k-chunk 16.
// LDS tiles stored TRANSPOSED ([kk][row]) so compute reads are contiguous
// float4 (ds_read_b128, conflict-free).
__global__ __launch_bounds__(256) void proj_gemm(
    const float* __restrict__ X, const float* __restrict__ W,
    const float* __restrict__ bias, float* __restrict__ out) {
  __shared__ float Xt[16][64];
  __shared__ float Wt[16][64];
  const int t = threadIdx.x;
  const int ty = t >> 4, tx = t & 15;
  const int m0 = blockIdx.y * 64, n0 = blockIdx.x * 64;
  const int lr = t >> 2;          // 0..63 tile row
  const int lc = (t & 3) << 2;    // 0,4,8,12 k-col within chunk
  float acc[4][4] = {};
  for (int k0 = 0; k0 < HID; k0 += 16) {
    const float4 xv = *reinterpret_cast<const float4*>(X + (size_t)(m0 + lr) * HID + k0 + lc);
    const float4 wv = *reinterpret_cast<const float4*>(W + (size_t)(n0 + lr) * HID + k0 + lc);
    __syncthreads();   // previous iteration's reads complete
    Xt[lc + 0][lr] = xv.x; Xt[lc + 1][lr] = xv.y; Xt[lc + 2][lr] = xv.z; Xt[lc + 3][lr] = xv.w;
    Wt[lc + 0][lr] = wv.x; Wt[lc + 1][lr] = wv.y; Wt[lc + 2][lr] = wv.z; Wt[lc + 3][lr] = wv.w;
    __syncthreads();
#pragma unroll
    for (int kk = 0; kk < 16; ++kk) {
      const float4 a4 = *reinterpret_cast<const float4*>(&Xt[kk][ty << 2]);
      const float4 b4 = *reinterpret_cast<const float4*>(&Wt[kk][tx << 2]);
      const float av[4] = {a4.x, a4.y, a4.z, a4.w};
      const float bv[4] = {b4.x, b4.y, b4.z, b4.w};
#pragma unroll
      for (int i = 0; i < 4; ++i)
#pragma unroll
        for (int j = 0; j < 4; ++j) acc[i][j] = fmaf(av[i], bv[j], acc[i][j]);
    }
  }
  const int n = n0 + (tx << 2);
  const float4 bb = *reinterpret_cast<const float4*>(bias + n);
#pragma unroll
  for (int i = 0; i < 4; ++i) {
    float4 o;
    o.x = acc[i][0] + bb.x; o.y = acc[i][1] + bb.y;
    o.z = acc[i][2] + bb.z; o.w = acc[i][3] + bb.w;
    *reinterpret_cast<float4*>(out + (size_t)(m0 + (ty << 2) + i) * HID + n) = o;
  }
}

// ---------------- Fused relative-position attention (fp32) ----------------
// score[q,k] = (Q[q]·K[k] + (Q[q]+K[k])·E[2047+q-k]) / 8 ; online softmax; O = P@V.
// Block: one (batch, head, 64-row q-tile). 256 threads = 16x16 grid, 4x4 each.
__global__ __launch_bounds__(256, 1) void attn_fp32(
    const float* __restrict__ Q, const float* __restrict__ K,
    const float* __restrict__ V, const float* __restrict__ E,
    float* __restrict__ out) {
  __shared__ float Qs[BQ][65];    // padded: scalar reads <=2-way conflicts
  __shared__ float Ks[BK][65];
  __shared__ float Es[NER][65];
  __shared__ float Vs[BK][64];    // row-major, float4 reads contiguous
  __shared__ float Pt[BK][68];    // P transposed [k][q]; stride 68 keeps 16B align
  const int t = threadIdx.x;
  const int ty = t >> 4, tx = t & 15;
  const int q0 = blockIdx.x * BQ;
  const int h = blockIdx.y, b = blockIdx.z;
  const size_t headoff = ((size_t)b * SEQ) * HID + (size_t)h * HD;

  // Q tile: BQ rows x 64, gathered from [.., h*64 .. h*64+63]
  for (int i = t; i < BQ * 16; i += 256) {
    const int r = i >> 4, c = (i & 15) << 2;
    const float4 v4 = *reinterpret_cast<const float4*>(Q + headoff + (size_t)(q0 + r) * HID + c);
    Qs[r][c + 0] = v4.x; Qs[r][c + 1] = v4.y; Qs[r][c + 2] = v4.z; Qs[r][c + 3] = v4.w;
  }

  float m[4], l[4], O[4][4];
#pragma unroll
  for (int i = 0; i < 4; ++i) {
    m[i] = -3.0e38f; l[i] = 0.0f;
#pragma unroll
    for (int j = 0; j < 4; ++j) O[i][j] = 0.0f;
  }

  for (int k0 = 0; k0 < SEQ; k0 += BK) {
    const int ebase = 2047 + q0 - k0 - (BK - 1);   // in [0, 3968]; +126 max = 4094: in-bounds
    __syncthreads();   // prior PV reads of Ks/Vs/Es/Pt complete
    for (int i = t; i < BK * 16; i += 256) {
      const int r = i >> 4, c = (i & 15) << 2;
      const float4 kv = *reinterpret_cast<const float4*>(K + headoff + (size_t)(k0 + r) * HID + c);
      const float4 vv = *reinterpret_cast<const float4*>(V + headoff + (size_t)(k0 + r) * HID + c);
      Ks[r][c + 0] = kv.x; Ks[r][c + 1] = kv.y; Ks[r][c + 2] = kv.z; Ks[r][c + 3] = kv.w;
      *reinterpret_cast<float4*>(&Vs[r][c]) = vv;
    }
    // E rows are CONTIGUOUS in dist_emb (rows ebase..ebase+126)
    for (int i = t; i < NER * 16; i += 256) {
      const int r = i >> 4, c = (i & 15) << 2;
      const float4 ev = *reinterpret_cast<const float4*>(E + (size_t)(ebase + r) * HD + c);
      Es[r][c + 0] = ev.x; Es[r][c + 1] = ev.y; Es[r][c + 2] = ev.z; Es[r][c + 3] = ev.w;
    }
    __syncthreads();

    // ---- scores: s[i][j] for q = q0+4ty+i, k = k0+4tx+j ----
    float s[4][4] = {};
    const int erow0 = (ty << 2) - (tx << 2) + 60;  // + (i-j+3) gives row (q-k)+63-ebase_local
#pragma unroll 2
    for (int dd = 0; dd < HD; ++dd) {
      float qa[4], kb[4], e7[7];
#pragma unroll
      for (int i = 0; i < 4; ++i) qa[i] = Qs[(ty << 2) + i][dd];
#pragma unroll
      for (int j = 0; j < 4; ++j) kb[j] = Ks[(tx << 2) + j][dd];
#pragma unroll
      for (int u = 0; u < 7; ++u) e7[u] = Es[erow0 + u][dd];
#pragma unroll
      for (int i = 0; i < 4; ++i)
#pragma unroll
        for (int j = 0; j < 4; ++j)
          s[i][j] += qa[i] * kb[j] + (qa[i] + kb[j]) * e7[i - j + 3];
    }
#pragma unroll
    for (int i = 0; i < 4; ++i)
#pragma unroll
      for (int j = 0; j < 4; ++j) s[i][j] *= 0.125f;

    // ---- online softmax (row state shared by the 16 tx lanes of each row) ----
    float tmax[4];
#pragma unroll
    for (int i = 0; i < 4; ++i)
      tmax[i] = fmaxf(fmaxf(s[i][0], s[i][1]), fmaxf(s[i][2], s[i][3]));
#pragma unroll
    for (int off = 1; off < 16; off <<= 1)
#pragma unroll
      for (int i = 0; i < 4; ++i) tmax[i] = fmaxf(tmax[i], __shfl_xor(tmax[i], off, 16));
    float rsum[4];
#pragma unroll
    for (int i = 0; i < 4; ++i) {
      const float mn = fmaxf(m[i], tmax[i]);
      const float corr = __expf(m[i] - mn);
      m[i] = mn;
      float rs = 0.0f;
#pragma unroll
      for (int j = 0; j < 4; ++j) { s[i][j] = __expf(s[i][j] - mn); rs += s[i][j]; }
      rsum[i] = rs;
      l[i] *= corr;
#pragma unroll
      for (int j = 0; j < 4; ++j) O[i][j] *= corr;
    }
#pragma unroll
    for (int off = 1; off < 16; off <<= 1)
#pragma unroll
      for (int i = 0; i < 4; ++i) rsum[i] += __shfl_xor(rsum[i], off, 16);
#pragma unroll
    for (int i = 0; i < 4; ++i) l[i] += rsum[i];

    // stage P transposed for the PV phase
#pragma unroll
    for (int i = 0; i < 4; ++i)
#pragma unroll
      for (int j = 0; j < 4; ++j) Pt[(tx << 2) + j][(ty << 2) + i] = s[i][j];
    __syncthreads();

    // ---- PV: O[i][j] += sum_k P[q,k] * V[k, d=4tx+j] ----
#pragma unroll 4
    for (int kk = 0; kk < BK; ++kk) {
      const float4 pv = *reinterpret_cast<const float4*>(&Pt[kk][ty << 2]);
      const float4 vv = *reinterpret_cast<const float4*>(&Vs[kk][tx << 2]);
      const float pa[4] = {pv.x, pv.y, pv.z, pv.w};
      const float vb[4] = {vv.x, vv.y, vv.z, vv.w};
#pragma unroll
      for (int i = 0; i < 4; ++i)
#pragma unroll
        for (int j = 0; j < 4; ++j) O[i][j] = fmaf(pa[i], vb[j], O[i][j]);
    }
  }

  // ---- epilogue: normalize and store ----
  const int n = h * HD + (tx << 2);
#pragma unroll
  for (int i = 0; i < 4; ++i) {
    const float inv = 1.0f / l[i];
    float4 o;
    o.x = O[i][0] * inv; o.y = O[i][1] * inv; o.z = O[i][2] * inv; o.w = O[i][3] * inv;
    *reinterpret_cast<float4*>(out + ((size_t)b * SEQ + q0 + (ty << 2) + i) * HID + n) = o;
  }
}

extern "C" void kernel_launch(void* const* d_in, const int* in_sizes, int n_in,
                              void* d_out, int out_size, void* d_ws, size_t ws_size,
                              hipStream_t stream) {
  const float* hs = (const float*)d_in[0];
  const float* Wq = (const float*)d_in[1];
  const float* bq = (const float*)d_in[2];
  const float* Wk = (const float*)d_in[3];
  const float* bk = (const float*)d_in[4];
  const float* Wv = (const float*)d_in[5];
  const float* bv = (const float*)d_in[6];
  const float* de = (const float*)d_in[7];
  float* out = (float*)d_out;

  const size_t per = (size_t)2 * SEQ * HID;   // 4,194,304 floats = 16 MB each
  float* Qw = (float*)d_ws;
  float* Kw = Qw + per;
  float* Vw = Kw + per;

  dim3 blk(256);
  dim3 gp(HID / 64, (2 * SEQ) / 64);          // (16, 64)
  hipLaunchKernelGGL(proj_gemm, gp, blk, 0, stream, hs, Wq, bq, Qw);
  hipLaunchKernelGGL(proj_gemm, gp, blk, 0, stream, hs, Wk, bk, Kw);
  hipLaunchKernelGGL(proj_gemm, gp, blk, 0, stream, hs, Wv, bv, Vw);

  dim3 ga(SEQ / BQ, NH, 2);                   // (32, 16, 2)
  hipLaunchKernelGGL(attn_fp32, ga, blk, 0, stream, Qw, Kw, Vw, de, out);
}

// Round 2
// 721.245 us; speedup vs baseline: 2.9084x; 2.9084x over previous
//
#include <hip/hip_runtime.h>

#define NH 16
#define HD 64
#define SEQ 2048
#define HID 1024
#define MAXP 2048

typedef float f32x4 __attribute__((ext_vector_type(4)));
typedef short bf16x8 __attribute__((ext_vector_type(8)));
typedef unsigned short u16;
typedef unsigned short u16x4 __attribute__((ext_vector_type(4)));
typedef unsigned short u16x8 __attribute__((ext_vector_type(8)));

__device__ __forceinline__ u16 f2bf(float x) {
  union { float f; unsigned u; } v; v.f = x;
  const unsigned r = (v.u + 0x7fffu + ((v.u >> 16) & 1u)) >> 16;  // RNE
  return (u16)r;
}
__device__ __forceinline__ float bf2f(u16 h) {
  union { unsigned u; float f; } v; v.u = ((unsigned)h) << 16;
  return v.f;
}

// XOR-swizzle for bf16 tiles with 64-elem (128B) row stride: 16B chunk index
// XORed with (row&7). Applied on BOTH write and read (involution).
#define SWZ(r, c) ((r) * 64 + ((((c) >> 3) ^ ((r) & 7)) << 3) + ((c) & 7))

// ---------------- Projection GEMM: out = bf16(X @ W^T + bias) ----------------
__global__ __launch_bounds__(256) void proj_gemm_bf16(
    const float* __restrict__ X, const float* __restrict__ W,
    const float* __restrict__ bias, u16* __restrict__ out) {
  __shared__ float Xt[16][64];
  __shared__ float Wt[16][64];
  const int t = threadIdx.x;
  const int ty = t >> 4, tx = t & 15;
  const int m0 = blockIdx.y * 64, n0 = blockIdx.x * 64;
  const int lr = t >> 2;
  const int lc = (t & 3) << 2;
  float acc[4][4] = {};
  for (int k0 = 0; k0 < HID; k0 += 16) {
    const float4 xv = *reinterpret_cast<const float4*>(X + (size_t)(m0 + lr) * HID + k0 + lc);
    const float4 wv = *reinterpret_cast<const float4*>(W + (size_t)(n0 + lr) * HID + k0 + lc);
    __syncthreads();
    Xt[lc + 0][lr] = xv.x; Xt[lc + 1][lr] = xv.y; Xt[lc + 2][lr] = xv.z; Xt[lc + 3][lr] = xv.w;
    Wt[lc + 0][lr] = wv.x; Wt[lc + 1][lr] = wv.y; Wt[lc + 2][lr] = wv.z; Wt[lc + 3][lr] = wv.w;
    __syncthreads();
#pragma unroll
    for (int kk = 0; kk < 16; ++kk) {
      const float4 a4 = *reinterpret_cast<const float4*>(&Xt[kk][ty << 2]);
      const float4 b4 = *reinterpret_cast<const float4*>(&Wt[kk][tx << 2]);
      const float av[4] = {a4.x, a4.y, a4.z, a4.w};
      const float bv[4] = {b4.x, b4.y, b4.z, b4.w};
#pragma unroll
      for (int i = 0; i < 4; ++i)
#pragma unroll
        for (int j = 0; j < 4; ++j) acc[i][j] = fmaf(av[i], bv[j], acc[i][j]);
    }
  }
  const int n = n0 + (tx << 2);
  const float4 bb = *reinterpret_cast<const float4*>(bias + n);
#pragma unroll
  for (int i = 0; i < 4; ++i) {
    u16x4 o;
    o[0] = f2bf(acc[i][0] + bb.x); o[1] = f2bf(acc[i][1] + bb.y);
    o[2] = f2bf(acc[i][2] + bb.z); o[3] = f2bf(acc[i][3] + bb.w);
    *reinterpret_cast<u16x4*>(out + (size_t)(m0 + (ty << 2) + i) * HID + n) = o;
  }
}

// ---------------- V transpose: Vt[b][h][d][s] <- V[b][s][h*64+d] ----------------
__global__ __launch_bounds__(256) void transpose_v(
    const u16* __restrict__ Vin, u16* __restrict__ Vt) {
  __shared__ u16 tile[64 * 65];
  const int t = threadIdx.x;
  const int s0 = blockIdx.x * 64, h = blockIdx.y, b = blockIdx.z;
  const int r = t >> 2, c0 = (t & 3) * 16;
  const u16* gp = Vin + (size_t)(b * SEQ + s0 + r) * HID + h * HD + c0;
  const u16x8 a0 = *reinterpret_cast<const u16x8*>(gp);
  const u16x8 a1 = *reinterpret_cast<const u16x8*>(gp + 8);
#pragma unroll
  for (int i = 0; i < 8; ++i) { tile[r * 65 + c0 + i] = a0[i]; tile[r * 65 + c0 + 8 + i] = a1[i]; }
  __syncthreads();
  const int d = t >> 2, sc = (t & 3) * 16;
  u16x8 o0, o1;
#pragma unroll
  for (int i = 0; i < 8; ++i) {
    o0[i] = tile[(sc + i) * 65 + d];
    o1[i] = tile[(sc + 8 + i) * 65 + d];
  }
  u16* op = Vt + ((size_t)(b * NH + h) * HD + d) * SEQ + s0 + sc;
  *reinterpret_cast<u16x8*>(op) = o0;
  *reinterpret_cast<u16x8*>(op + 8) = o1;
}

// ---------------- dist_emb fp32 -> bf16 ----------------
__global__ void cvt_e_kernel(const float* __restrict__ E, u16* __restrict__ Eb) {
  const int i = blockIdx.x * 256 + threadIdx.x;
  if (i < (2 * MAXP - 1) * HD / 4) {
    const float4 v = *reinterpret_cast<const float4*>(E + (size_t)i * 4);
    u16x4 o;
    o[0] = f2bf(v.x); o[1] = f2bf(v.y); o[2] = f2bf(v.z); o[3] = f2bf(v.w);
    *reinterpret_cast<u16x4*>(Eb + (size_t)i * 4) = o;
  }
}

// ---------------- Fused MFMA attention with Toeplitz rel-pos ----------------
// Per block: (b, h, 64-q-tile). 4 waves; wave w owns q rows [16w,16w+16).
// Per 64-k-tile: Rq = Q·E^T, Rk = K·E^T (64x128x64 GEMMs, E-tile = 127
// contiguous dist_emb rows), S = Q·K^T; score = (S + Rq[q][j] + Rk[k][j])/8
// with j = qi-ki+63; online softmax; O += P·V via Vt.
__global__ __launch_bounds__(256, 2) void attn_mfma(
    const u16* __restrict__ Q, const u16* __restrict__ K,
    const u16* __restrict__ Vt, const u16* __restrict__ E,
    float* __restrict__ out) {
  __shared__ u16 sK[64 * 64];
  __shared__ u16 sV[64 * 64];
  __shared__ u16 sP[64 * 64];
  __shared__ u16 sE[128 * 64];
  __shared__ u16 sRq[64 * 128];
  __shared__ u16 sRk[64 * 128];

  const int t = threadIdx.x;
  const int lane = t & 63;
  const int w = t >> 6;
  const int g = lane >> 4;     // row-group within wave (C-layout rows 4g..4g+3)
  const int li = lane & 15;    // column / row index within fragment
  const int q0 = blockIdx.x * 64;
  const int h = blockIdx.y, b = blockIdx.z;
  const size_t qkbase = (size_t)b * SEQ * HID + (size_t)h * HD;
  const size_t vtbase = (size_t)(b * NH + h) * HD * SEQ;

  const int str = t >> 2, stc = (t & 3) * 16;  // K/V staging: 64 rows x 4x16
  const int ser = t >> 1, sec = (t & 1) * 32;  // E staging: 128 rows x 2x32

  // Q A-fragments (lane: row = q0+16w+li, k = 32c+8g..+7), persistent
  bf16x8 qA[2];
#pragma unroll
  for (int c = 0; c < 2; ++c)
    qA[c] = *reinterpret_cast<const bf16x8*>(
        Q + qkbase + (size_t)(q0 + 16 * w + li) * HID + 32 * c + 8 * g);

  f32x4 accO[4];
  float mrow[4], lrow[4];
#pragma unroll
  for (int n = 0; n < 4; ++n) accO[n] = (f32x4)0.0f;
#pragma unroll
  for (int r = 0; r < 4; ++r) { mrow[r] = -3.0e38f; lrow[r] = 0.0f; }

  for (int k0 = 0; k0 < SEQ; k0 += 64) {
    const int ebase = 1984 + q0 - k0;  // dist_emb row of local j=0; in [0,3968]
    __syncthreads();                   // prior-iter LDS readers done
    {
      const u16* gk = K + qkbase + (size_t)(k0 + str) * HID + stc;
      const u16x8 a0 = *reinterpret_cast<const u16x8*>(gk);
      const u16x8 a1 = *reinterpret_cast<const u16x8*>(gk + 8);
      *reinterpret_cast<u16x8*>(&sK[SWZ(str, stc)]) = a0;
      *reinterpret_cast<u16x8*>(&sK[SWZ(str, stc + 8)]) = a1;
      const u16* gv = Vt + vtbase + (size_t)str * SEQ + k0 + stc;
      const u16x8 v0 = *reinterpret_cast<const u16x8*>(gv);
      const u16x8 v1 = *reinterpret_cast<const u16x8*>(gv + 8);
      *reinterpret_cast<u16x8*>(&sV[SWZ(str, stc)]) = v0;
      *reinterpret_cast<u16x8*>(&sV[SWZ(str, stc + 8)]) = v1;
      const int er = min(ebase + ser, 2 * MAXP - 2);  // row 127 unused; clamp in-bounds
      const u16* ge = E + (size_t)er * HD + sec;
#pragma unroll
      for (int u = 0; u < 4; ++u) {
        const u16x8 ev = *reinterpret_cast<const u16x8*>(ge + 8 * u);
        *reinterpret_cast<u16x8*>(&sE[SWZ(ser, sec + 8 * u)]) = ev;
      }
    }
    __syncthreads();

    // ---- Rq = Q·E^T, Rk = K·E^T (wave w: q/k rows 16w..16w+15, all 128 j) ----
    bf16x8 kA[2];
#pragma unroll
    for (int c = 0; c < 2; ++c)
      kA[c] = *reinterpret_cast<const bf16x8*>(&sK[SWZ(16 * w + li, 32 * c + 8 * g)]);
    f32x4 aqe[8], ake[8];
#pragma unroll
    for (int m = 0; m < 8; ++m) {
      aqe[m] = (f32x4)0.0f; ake[m] = (f32x4)0.0f;
#pragma unroll
      for (int c = 0; c < 2; ++c) {
        const bf16x8 eB = *reinterpret_cast<const bf16x8*>(&sE[SWZ(16 * m + li, 32 * c + 8 * g)]);
        aqe[m] = __builtin_amdgcn_mfma_f32_16x16x32_bf16(qA[c], eB, aqe[m], 0, 0, 0);
        ake[m] = __builtin_amdgcn_mfma_f32_16x16x32_bf16(kA[c], eB, ake[m], 0, 0, 0);
      }
    }
#pragma unroll
    for (int m = 0; m < 8; ++m)
#pragma unroll
      for (int r = 0; r < 4; ++r) {
        sRq[(16 * w + 4 * g + r) * 128 + 16 * m + li] = f2bf(aqe[m][r]);
        sRk[(16 * w + 4 * g + r) * 128 + 16 * m + li] = f2bf(ake[m][r]);
      }

    // ---- S = Q·K^T ----
    f32x4 aqk[4];
#pragma unroll
    for (int n = 0; n < 4; ++n) {
      aqk[n] = (f32x4)0.0f;
#pragma unroll
      for (int c = 0; c < 2; ++c) {
        const bf16x8 kB = *reinterpret_cast<const bf16x8*>(&sK[SWZ(16 * n + li, 32 * c + 8 * g)]);
        aqk[n] = __builtin_amdgcn_mfma_f32_16x16x32_bf16(qA[c], kB, aqk[n], 0, 0, 0);
      }
    }
    __syncthreads();  // Rq/Rk visible to all waves

    // ---- score assembly + online softmax ----
    float sc[4][4], tmax[4];
#pragma unroll
    for (int r = 0; r < 4; ++r) tmax[r] = -3.0e38f;
#pragma unroll
    for (int n = 0; n < 4; ++n) {
      const int ki = 16 * n + li;
#pragma unroll
      for (int r = 0; r < 4; ++r) {
        const int qi = 16 * w + 4 * g + r;
        const int j = qi - ki + 63;  // in [0,126]
        const float sv = (aqk[n][r] + bf2f(sRq[qi * 128 + j]) + bf2f(sRk[ki * 128 + j])) * 0.125f;
        sc[n][r] = sv;
        tmax[r] = fmaxf(tmax[r], sv);
      }
    }
#pragma unroll
    for (int off = 1; off < 16; off <<= 1)
#pragma unroll
      for (int r = 0; r < 4; ++r) tmax[r] = fmaxf(tmax[r], __shfl_xor(tmax[r], off, 16));
    float rsum[4];
#pragma unroll
    for (int r = 0; r < 4; ++r) {
      const float mn = fmaxf(mrow[r], tmax[r]);
      const float corr = __expf(mrow[r] - mn);
      mrow[r] = mn; lrow[r] *= corr;
#pragma unroll
      for (int n = 0; n < 4; ++n) accO[n][r] *= corr;
      rsum[r] = 0.0f;
    }
#pragma unroll
    for (int n = 0; n < 4; ++n)
#pragma unroll
      for (int r = 0; r < 4; ++r) {
        const float p = __expf(sc[n][r] - mrow[r]);
        rsum[r] += p;
        sP[SWZ(16 * w + 4 * g + r, 16 * n + li)] = f2bf(p);
      }
#pragma unroll
    for (int off = 1; off < 16; off <<= 1)
#pragma unroll
      for (int r = 0; r < 4; ++r) rsum[r] += __shfl_xor(rsum[r], off, 16);
#pragma unroll
    for (int r = 0; r < 4; ++r) lrow[r] += rsum[r];
    __syncthreads();  // P visible

    // ---- O += P·V ----
    bf16x8 pA[2];
#pragma unroll
    for (int c = 0; c < 2; ++c)
      pA[c] = *reinterpret_cast<const bf16x8*>(&sP[SWZ(16 * w + li, 32 * c + 8 * g)]);
#pragma unroll
    for (int n = 0; n < 4; ++n)
#pragma unroll
      for (int c = 0; c < 2; ++c) {
        const bf16x8 vB = *reinterpret_cast<const bf16x8*>(&sV[SWZ(16 * n + li, 32 * c + 8 * g)]);
        accO[n] = __builtin_amdgcn_mfma_f32_16x16x32_bf16(pA[c], vB, accO[n], 0, 0, 0);
      }
  }

  // ---- epilogue ----
#pragma unroll
  for (int r = 0; r < 4; ++r) {
    const float inv = 1.0f / lrow[r];
    const size_t row = (size_t)(b * SEQ + q0 + 16 * w + 4 * g + r) * HID + h * HD;
#pragma unroll
    for (int n = 0; n < 4; ++n) out[row + 16 * n + li] = accO[n][r] * inv;
  }
}

extern "C" void kernel_launch(void* const* d_in, const int* in_sizes, int n_in,
                              void* d_out, int out_size, void* d_ws, size_t ws_size,
                              hipStream_t stream) {
  const float* hs = (const float*)d_in[0];
  const float* Wq = (const float*)d_in[1];
  const float* bq = (const float*)d_in[2];
  const float* Wk = (const float*)d_in[3];
  const float* bk = (const float*)d_in[4];
  const float* Wv = (const float*)d_in[5];
  const float* bv = (const float*)d_in[6];
  const float* de = (const float*)d_in[7];
  float* out = (float*)d_out;

  const size_t per = (size_t)2 * SEQ * HID;  // 4,194,304 bf16 elems = 8 MB each
  u16* Qb = (u16*)d_ws;
  u16* Kb = Qb + per;
  u16* Vb = Kb + per;
  u16* Vtb = Vb + per;
  u16* Eb = Vtb + per;  // 262,080 elems

  dim3 blk(256);
  dim3 gp(HID / 64, (2 * SEQ) / 64);  // (16, 64)
  hipLaunchKernelGGL(proj_gemm_bf16, gp, blk, 0, stream, hs, Wq, bq, Qb);
  hipLaunchKernelGGL(proj_gemm_bf16, gp, blk, 0, stream, hs, Wk, bk, Kb);
  hipLaunchKernelGGL(proj_gemm_bf16, gp, blk, 0, stream, hs, Wv, bv, Vb);
  hipLaunchKernelGGL(transpose_v, dim3(SEQ / 64, NH, 2), blk, 0, stream, Vb, Vtb);
  hipLaunchKernelGGL(cvt_e_kernel, dim3(256), blk, 0, stream, de, Eb);
  hipLaunchKernelGGL(attn_mfma, dim3(SEQ / 64, NH, 2), blk, 0, stream, Qb, Kb, Vtb, Eb, out);
}

// Round 5
// 293.317 us; speedup vs baseline: 7.1515x; 2.4589x over previous
//
#include <hip/hip_runtime.h>
#include <hip/hip_bf16.h>

#define NH 16
#define HD 64
#define SEQ 2048
#define HID 1024
#define MAXP 2048
#define ST_R 72   // u16 stride of transposed R tiles (144B: 8B-aligned, odd-ish banks)

typedef float f32x4 __attribute__((ext_vector_type(4)));
typedef short bf16x8 __attribute__((ext_vector_type(8)));
typedef unsigned short u16;
typedef unsigned short u16x8 __attribute__((ext_vector_type(8)));

__device__ __forceinline__ u16 f2bf_hw(float x) {
  union { __hip_bfloat16 h; u16 u; } v;
  v.h = __float2bfloat16(x);
  return v.u;
}
__device__ __forceinline__ unsigned pk2(float a, float b) {
  return (unsigned)f2bf_hw(a) | ((unsigned)f2bf_hw(b) << 16);
}
__device__ __forceinline__ float bf2f(u16 h) {
  union { unsigned u; float f; } v; v.u = ((unsigned)h) << 16;
  return v.f;
}

// XOR-swizzle for bf16 tiles with 64-elem (128B) row stride.
#define SWZ(r, c) ((r) * 64 + ((((c) >> 3) ^ ((r) & 7)) << 3) + ((c) & 7))

// async global->LDS 16B: LDS dest = wave-uniform base + lane*16; global src per-lane.
__device__ __forceinline__ void async_copy16(void* lds, const void* g) {
  __builtin_amdgcn_global_load_lds(
      (const __attribute__((address_space(1))) unsigned int*)g,
      (__attribute__((address_space(3))) unsigned int*)lds, 16, 0, 0);
}

// ---------------- fp32 -> bf16 bulk convert ----------------
__global__ __launch_bounds__(256) void cvt_f32_bf16(
    const float* __restrict__ src, u16* __restrict__ dst, int n4) {
  int i = blockIdx.x * 256 + threadIdx.x;
  const int stride = gridDim.x * 256;
  for (; i < n4; i += stride) {
    const float4 v = reinterpret_cast<const float4*>(src)[i];
    uint2 d;
    d.x = pk2(v.x, v.y);
    d.y = pk2(v.z, v.w);
    reinterpret_cast<uint2*>(dst)[i] = d;
  }
}

// ---------------- Fused Q/K/V projection: O = bf16(X @ W^T + b) ----------------
// 128x128 tile, BK=64, 4 waves (2x2 quadrants of 64x64), global_load_lds staging
// with pre-swizzled source so SWZ fragment reads are conflict-free (T2).
__global__ __launch_bounds__(256) void proj_mfma(
    const u16* __restrict__ Xb, const u16* __restrict__ W0,
    const u16* __restrict__ W1, const u16* __restrict__ W2,
    const float* __restrict__ b0, const float* __restrict__ b1,
    const float* __restrict__ b2,
    u16* __restrict__ O0, u16* __restrict__ O1, u16* __restrict__ O2) {
  __shared__ u16 sA[128 * 64];
  __shared__ u16 sB[128 * 64];
  const int t = threadIdx.x, lane = t & 63, w = t >> 6;
  const int g = lane >> 4, li = lane & 15;
  const int wsel = blockIdx.x >> 3;
  const int n0 = (blockIdx.x & 7) * 128, m0 = blockIdx.y * 128;
  const u16* Wb = wsel == 0 ? W0 : (wsel == 1 ? W1 : W2);
  const float* bias = wsel == 0 ? b0 : (wsel == 1 ? b1 : b2);
  u16* Ob = wsel == 0 ? O0 : (wsel == 1 ? O1 : O2);
  const int wr = w >> 1, wc = w & 1;

  f32x4 acc[4][4];
#pragma unroll
  for (int i = 0; i < 4; ++i)
#pragma unroll
    for (int j = 0; j < 4; ++j) acc[i][j] = (f32x4)0.0f;

  for (int k0 = 0; k0 < HID; k0 += 64) {
    __syncthreads();
#pragma unroll
    for (int i = 0; i < 4; ++i) {
      const int idx = (w * 4 + i) * 64 + lane;
      const int row = idx >> 3, sch = (idx & 7) ^ (row & 7);
      async_copy16(&sA[(w * 4 + i) * 512], Xb + (size_t)(m0 + row) * HID + k0 + sch * 8);
      async_copy16(&sB[(w * 4 + i) * 512], Wb + (size_t)(n0 + row) * HID + k0 + sch * 8);
    }
    __syncthreads();
    bf16x8 af[4][2], bfr[4][2];
#pragma unroll
    for (int i = 0; i < 4; ++i)
#pragma unroll
      for (int c = 0; c < 2; ++c)
        af[i][c] = *reinterpret_cast<const bf16x8*>(&sA[SWZ(wr * 64 + 16 * i + li, 32 * c + 8 * g)]);
#pragma unroll
    for (int j = 0; j < 4; ++j)
#pragma unroll
      for (int c = 0; c < 2; ++c)
        bfr[j][c] = *reinterpret_cast<const bf16x8*>(&sB[SWZ(wc * 64 + 16 * j + li, 32 * c + 8 * g)]);
#pragma unroll
    for (int i = 0; i < 4; ++i)
#pragma unroll
      for (int j = 0; j < 4; ++j)
#pragma unroll
        for (int c = 0; c < 2; ++c)
          acc[i][j] = __builtin_amdgcn_mfma_f32_16x16x32_bf16(af[i][c], bfr[j][c], acc[i][j], 0, 0, 0);
  }

#pragma unroll
  for (int j = 0; j < 4; ++j) {
    const float bj = bias[n0 + wc * 64 + 16 * j + li];
#pragma unroll
    for (int i = 0; i < 4; ++i)
#pragma unroll
      for (int r = 0; r < 4; ++r)
        Ob[(size_t)(m0 + wr * 64 + 16 * i + 4 * g + r) * HID + n0 + wc * 64 + 16 * j + li] =
            f2bf_hw(acc[i][j][r] + bj);
  }
}

// ---------------- V transpose: Vt[b][h][d][s] <- V[b][s][h*64+d] ----------------
__global__ __launch_bounds__(256) void transpose_v(
    const u16* __restrict__ Vin, u16* __restrict__ Vt) {
  __shared__ u16 tile[64 * 65];
  const int t = threadIdx.x;
  const int s0 = blockIdx.x * 64, h = blockIdx.y, b = blockIdx.z;
  const int r = t >> 2, c0 = (t & 3) * 16;
  const u16* gp = Vin + (size_t)(b * SEQ + s0 + r) * HID + h * HD + c0;
  const u16x8 a0 = *reinterpret_cast<const u16x8*>(gp);
  const u16x8 a1 = *reinterpret_cast<const u16x8*>(gp + 8);
#pragma unroll
  for (int i = 0; i < 8; ++i) { tile[r * 65 + c0 + i] = a0[i]; tile[r * 65 + c0 + 8 + i] = a1[i]; }
  __syncthreads();
  const int d = t >> 2, sc = (t & 3) * 16;
  u16x8 o0, o1;
#pragma unroll
  for (int i = 0; i < 8; ++i) {
    o0[i] = tile[(sc + i) * 65 + d];
    o1[i] = tile[(sc + 8 + i) * 65 + d];
  }
  u16* op = Vt + ((size_t)(b * NH + h) * HD + d) * SEQ + s0 + sc;
  *reinterpret_cast<u16x8*>(op) = o0;
  *reinterpret_cast<u16x8*>(op + 8) = o1;
}

// ---------------- Fused MFMA attention, Toeplitz rel-pos, Rq ring ----------------
// Per block: (b,h,64 q-rows), 4 waves. E ring: 128 slots, slot = global_E_row & 127.
// Per k-tile: stage K,V + 64 NEW E rows (128 on iter 0); Rk = K·E_ring (all slots),
// Rq = Q·E_new (4 m-groups; all 8 on iter 0, retained in LDS ring);
// S = Q·K^T; score = (S + Rq[q][slot] + Rk[k][slot])/8, slot=(sb+qi-ki+63)&127;
// online softmax; O += P·V.
__global__ __launch_bounds__(256, 2) void attn_mfma2(
    const u16* __restrict__ Q, const u16* __restrict__ K,
    const u16* __restrict__ Vt, const u16* __restrict__ E,
    float* __restrict__ out) {
  __shared__ u16 sK[64 * 64];
  __shared__ u16 sV[64 * 64];
  __shared__ u16 sP[64 * 64];
  __shared__ u16 sE[128 * 64];
  __shared__ u16 sRq[128 * ST_R];   // [slot][q] (transposed)
  __shared__ u16 sRk[128 * ST_R];   // [slot][k]

  const int t = threadIdx.x;
  const int lane = t & 63, w = t >> 6;
  const int g = lane >> 4, li = lane & 15;
  const int q0 = blockIdx.x * 64;
  const int h = blockIdx.y, b = blockIdx.z;
  const size_t qkbase = (size_t)b * SEQ * HID + (size_t)h * HD;
  const size_t vtbase = (size_t)(b * NH + h) * HD * SEQ;

  bf16x8 qA[2];
#pragma unroll
  for (int c = 0; c < 2; ++c)
    qA[c] = *reinterpret_cast<const bf16x8*>(
        Q + qkbase + (size_t)(q0 + 16 * w + li) * HID + 32 * c + 8 * g);

  f32x4 accO[4];
  float mrow[4], lrow[4];
#pragma unroll
  for (int n = 0; n < 4; ++n) accO[n] = (f32x4)0.0f;
#pragma unroll
  for (int r = 0; r < 4; ++r) { mrow[r] = -3.0e38f; lrow[r] = 0.0f; }

  for (int k0 = 0; k0 < SEQ; k0 += 64) {
    const int eb = 1984 + q0 - k0;   // global E row of ring slot sb
    const int sb = eb & 127;         // 0 or 64
    __syncthreads();                 // prior-iter consumers done
    // ---- stage K, V, E(new window) via global_load_lds (pre-swizzled source) ----
#pragma unroll
    for (int i = 0; i < 2; ++i) {
      const int idx = (w * 2 + i) * 64 + lane;
      const int row = idx >> 3, sch = (idx & 7) ^ (row & 7);
      async_copy16(&sK[(w * 2 + i) * 512], K + qkbase + (size_t)(k0 + row) * HID + sch * 8);
      async_copy16(&sV[(w * 2 + i) * 512], Vt + vtbase + (size_t)row * SEQ + k0 + sch * 8);
      const int er = min(eb + row, 2 * MAXP - 2);
      async_copy16(&sE[sb * 64 + (w * 2 + i) * 512], E + (size_t)er * HD + sch * 8);
    }
    if (k0 == 0) {  // also stage upper 64 rows into the other ring half
#pragma unroll
      for (int i = 0; i < 2; ++i) {
        const int idx = (w * 2 + i) * 64 + lane;
        const int row = idx >> 3, sch = (idx & 7) ^ (row & 7);
        const int er = min(eb + 64 + row, 2 * MAXP - 2);
        async_copy16(&sE[(sb ^ 64) * 64 + (w * 2 + i) * 512], E + (size_t)er * HD + sch * 8);
      }
    }
    __syncthreads();

    // ---- R phase: Rk (all 8 slot-groups), Rq (new window only after iter 0) ----
    bf16x8 kA[2];
#pragma unroll
    for (int c = 0; c < 2; ++c)
      kA[c] = *reinterpret_cast<const bf16x8*>(&sK[SWZ(16 * w + li, 32 * c + 8 * g)]);
    const int mlo = sb >> 4;  // 0 or 4
    f32x4 ake[8], aqe[8];
#pragma unroll
    for (int m = 0; m < 8; ++m) {
      bf16x8 eB[2];
#pragma unroll
      for (int c = 0; c < 2; ++c)
        eB[c] = *reinterpret_cast<const bf16x8*>(&sE[SWZ(16 * m + li, 32 * c + 8 * g)]);
      ake[m] = (f32x4)0.0f;
#pragma unroll
      for (int c = 0; c < 2; ++c)
        ake[m] = __builtin_amdgcn_mfma_f32_16x16x32_bf16(kA[c], eB[c], ake[m], 0, 0, 0);
      if (k0 == 0 || (m >= mlo && m < mlo + 4)) {
        aqe[m] = (f32x4)0.0f;
#pragma unroll
        for (int c = 0; c < 2; ++c)
          aqe[m] = __builtin_amdgcn_mfma_f32_16x16x32_bf16(qA[c], eB[c], aqe[m], 0, 0, 0);
      }
    }

    // ---- S = Q·K^T ----
    f32x4 aqk[4];
#pragma unroll
    for (int n = 0; n < 4; ++n) {
      aqk[n] = (f32x4)0.0f;
#pragma unroll
      for (int c = 0; c < 2; ++c) {
        const bf16x8 kB = *reinterpret_cast<const bf16x8*>(&sK[SWZ(16 * n + li, 32 * c + 8 * g)]);
        aqk[n] = __builtin_amdgcn_mfma_f32_16x16x32_bf16(qA[c], kB, aqk[n], 0, 0, 0);
      }
    }

    // ---- write R transposed+packed: sR[slot=16m+li][col base 16w+4g], u16x4 ----
#pragma unroll
    for (int m = 0; m < 8; ++m) {
      uint2 d;
      d.x = pk2(ake[m][0], ake[m][1]);
      d.y = pk2(ake[m][2], ake[m][3]);
      *reinterpret_cast<uint2*>(&sRk[(16 * m + li) * ST_R + 16 * w + 4 * g]) = d;
      if (k0 == 0 || (m >= mlo && m < mlo + 4)) {
        uint2 e;
        e.x = pk2(aqe[m][0], aqe[m][1]);
        e.y = pk2(aqe[m][2], aqe[m][3]);
        *reinterpret_cast<uint2*>(&sRq[(16 * m + li) * ST_R + 16 * w + 4 * g]) = e;
      }
    }
    __syncthreads();  // R visible to all waves

    // ---- score assembly + online softmax ----
    float sc_[4][4], tmax[4];
#pragma unroll
    for (int r = 0; r < 4; ++r) tmax[r] = -3.0e38f;
#pragma unroll
    for (int n = 0; n < 4; ++n) {
      const int ki = 16 * n + li;
#pragma unroll
      for (int r = 0; r < 4; ++r) {
        const int qi = 16 * w + 4 * g + r;
        const int slot = (sb + qi - ki + 63) & 127;
        const float relq = bf2f(sRq[slot * ST_R + qi]);
        const float relk = bf2f(sRk[slot * ST_R + ki]);
        const float sv = (aqk[n][r] + relq + relk) * 0.125f;
        sc_[n][r] = sv;
        tmax[r] = fmaxf(tmax[r], sv);
      }
    }
#pragma unroll
    for (int off = 1; off < 16; off <<= 1)
#pragma unroll
      for (int r = 0; r < 4; ++r) tmax[r] = fmaxf(tmax[r], __shfl_xor(tmax[r], off, 16));
    float rsum[4];
#pragma unroll
    for (int r = 0; r < 4; ++r) {
      const float mn = fmaxf(mrow[r], tmax[r]);
      const float corr = __expf(mrow[r] - mn);
      mrow[r] = mn; lrow[r] *= corr;
#pragma unroll
      for (int n = 0; n < 4; ++n) accO[n][r] *= corr;
      rsum[r] = 0.0f;
    }
#pragma unroll
    for (int n = 0; n < 4; ++n)
#pragma unroll
      for (int r = 0; r < 4; ++r) {
        const float p = __expf(sc_[n][r] - mrow[r]);
        rsum[r] += p;
        sP[SWZ(16 * w + 4 * g + r, 16 * n + li)] = f2bf_hw(p);
      }
#pragma unroll
    for (int off = 1; off < 16; off <<= 1)
#pragma unroll
      for (int r = 0; r < 4; ++r) rsum[r] += __shfl_xor(rsum[r], off, 16);
#pragma unroll
    for (int r = 0; r < 4; ++r) lrow[r] += rsum[r];
    __syncthreads();  // P visible

    // ---- O += P·V ----
    bf16x8 pA[2];
#pragma unroll
    for (int c = 0; c < 2; ++c)
      pA[c] = *reinterpret_cast<const bf16x8*>(&sP[SWZ(16 * w + li, 32 * c + 8 * g)]);
#pragma unroll
    for (int n = 0; n < 4; ++n)
#pragma unroll
      for (int c = 0; c < 2; ++c) {
        const bf16x8 vB = *reinterpret_cast<const bf16x8*>(&sV[SWZ(16 * n + li, 32 * c + 8 * g)]);
        accO[n] = __builtin_amdgcn_mfma_f32_16x16x32_bf16(pA[c], vB, accO[n], 0, 0, 0);
      }
  }

  // ---- epilogue ----
#pragma unroll
  for (int r = 0; r < 4; ++r) {
    const float inv = 1.0f / lrow[r];
    const size_t row = (size_t)(b * SEQ + q0 + 16 * w + 4 * g + r) * HID + h * HD;
#pragma unroll
    for (int n = 0; n < 4; ++n) out[row + 16 * n + li] = accO[n][r] * inv;
  }
}

extern "C" void kernel_launch(void* const* d_in, const int* in_sizes, int n_in,
                              void* d_out, int out_size, void* d_ws, size_t ws_size,
                              hipStream_t stream) {
  const float* hs = (const float*)d_in[0];
  const float* Wq = (const float*)d_in[1];
  const float* bq = (const float*)d_in[2];
  const float* Wk = (const float*)d_in[3];
  const float* bk = (const float*)d_in[4];
  const float* Wv = (const float*)d_in[5];
  const float* bv = (const float*)d_in[6];
  const float* de = (const float*)d_in[7];
  float* out = (float*)d_out;

  // Sizes: hs = 2*2048*1024 = 4,194,304 floats; W* = 1,048,576; de = 262,080.
  u16* Xb  = (u16*)d_ws;                 // 4,194,304 u16
  u16* Wqb = Xb + (size_t)4194304;       // 1,048,576 each
  u16* Wkb = Wqb + (size_t)1048576;
  u16* Wvb = Wkb + (size_t)1048576;
  u16* Qb  = Wvb + (size_t)1048576;      // 4,194,304 each
  u16* Kb  = Qb + (size_t)4194304;
  u16* Vb  = Kb + (size_t)4194304;
  u16* Eb  = Vb + (size_t)4194304;       // 262,080
  u16* Vtb = Xb;                         // alias: Xb dead after proj_mfma

  dim3 blk(256);
  hipLaunchKernelGGL(cvt_f32_bf16, dim3(512), blk, 0, stream, hs, Xb, 1048576);
  hipLaunchKernelGGL(cvt_f32_bf16, dim3(256), blk, 0, stream, Wq, Wqb, 262144);
  hipLaunchKernelGGL(cvt_f32_bf16, dim3(256), blk, 0, stream, Wk, Wkb, 262144);
  hipLaunchKernelGGL(cvt_f32_bf16, dim3(256), blk, 0, stream, Wv, Wvb, 262144);
  hipLaunchKernelGGL(cvt_f32_bf16, dim3(128), blk, 0, stream, de, Eb, 65520);

  hipLaunchKernelGGL(proj_mfma, dim3(24, 32), blk, 0, stream,
                     Xb, Wqb, Wkb, Wvb, bq, bk, bv, Qb, Kb, Vb);
  hipLaunchKernelGGL(transpose_v, dim3(SEQ / 64, NH, 2), blk, 0, stream, Vb, Vtb);
  hipLaunchKernelGGL(attn_mfma2, dim3(SEQ / 64, NH, 2), blk, 0, stream, Qb, Kb, Vtb, Eb, out);
}